// Round 2
// baseline (264.523 us; speedup 1.0000x reference)
//
#include <hip/hip_runtime.h>

typedef __attribute__((ext_vector_type(8))) short bf16x8;
typedef __attribute__((ext_vector_type(4))) float f32x4;

#define MFMA(a, b, c) __builtin_amdgcn_mfma_f32_16x16x32_bf16(a, b, c, 0, 0, 0)

__device__ __forceinline__ unsigned short f2bf(float f) {
    unsigned u = __builtin_bit_cast(unsigned, f);
    u += 0x7fffu + ((u >> 16) & 1u);
    return (unsigned short)(u >> 16);
}

// ---------------- pass A: convert / transpose / rope tables ----------------

__global__ __launch_bounds__(256) void cvt_bf16(const float* __restrict__ in,
                                                unsigned short* __restrict__ out, int n) {
    int i = (blockIdx.x * 256 + threadIdx.x) * 4;
    if (i < n) {
        float4 f = *(const float4*)(in + i);
        ushort4 u;
        u.x = f2bf(f.x); u.y = f2bf(f.y); u.z = f2bf(f.z); u.w = f2bf(f.w);
        *(ushort4*)(out + i) = u;
    }
}

// in: [R, C] fp32 row-major  ->  out: [C, R] bf16 row-major
__global__ __launch_bounds__(256) void transpose_cvt(const float* __restrict__ in,
                                                     unsigned short* __restrict__ out,
                                                     int R, int C) {
    __shared__ float tile[32][33];
    const int c0 = blockIdx.x * 32, r0 = blockIdx.y * 32;
    const int tr = threadIdx.x >> 3;
    const int j4 = (threadIdx.x & 7) * 4;
    float4 f = *(const float4*)(in + (size_t)(r0 + tr) * C + c0 + j4);
    tile[tr][j4 + 0] = f.x; tile[tr][j4 + 1] = f.y;
    tile[tr][j4 + 2] = f.z; tile[tr][j4 + 3] = f.w;
    __syncthreads();
    ushort4 u;
    u.x = f2bf(tile[j4 + 0][tr]); u.y = f2bf(tile[j4 + 1][tr]);
    u.z = f2bf(tile[j4 + 2][tr]); u.w = f2bf(tile[j4 + 3][tr]);
    *(ushort4*)(out + (size_t)(c0 + tr) * R + r0 + j4) = u;
}

// accurate RoPE tables: cosT/sinT [2048][32] fp32  (libm sincosf does proper
// range reduction; native v_sin_f32 is undefined past +-256 revolutions)
__global__ __launch_bounds__(256) void rope_tab(float* __restrict__ cosT,
                                                float* __restrict__ sinT) {
    int i = blockIdx.x * 256 + threadIdx.x;       // 2048*32 = 65536
    int n = i >> 5, f = i & 31;
    float ang = (float)n * exp2f((float)f * -0.4152410118609203f);
    float s, c;
    sincosf(ang, &s, &c);
    cosT[i] = c; sinT[i] = s;
}

// ---------------- GEMM (A [M,K] bf16) x (Bt [N,K] bf16) ----------------
// EPI 0: qkv projection epilogue: RoPE on q,k; q,k -> [B,H,N,D]; v -> [B,H,D,N]
// EPI 1: plain fp32 store to out [M, Ncols]

template <int EPI>
__global__ __launch_bounds__(256, 2) void gemm_bt(const unsigned short* __restrict__ A,
                                                  const unsigned short* __restrict__ Bt,
                                                  int K, int Ncols,
                                                  unsigned short* __restrict__ oq,
                                                  unsigned short* __restrict__ ok,
                                                  unsigned short* __restrict__ ovt,
                                                  float* __restrict__ of,
                                                  const float* __restrict__ cosT,
                                                  const float* __restrict__ sinT) {
    __shared__ unsigned short As[128 * 40];
    __shared__ unsigned short Bs[128 * 40];
    const int tid = threadIdx.x;
    const int w = tid >> 6, lane = tid & 63, quad = lane >> 4, cc = lane & 15;
    const int wm = w >> 1, wn = w & 1;
    const int m0 = blockIdx.y * 128, n0 = blockIdx.x * 128;

    f32x4 acc[4][4] = {};
    const int srow = tid >> 1, shalf = tid & 1;
    const size_t arow = (size_t)(m0 + srow) * K;
    const size_t brow = (size_t)(n0 + srow) * K;

    for (int kt = 0; kt < K; kt += 32) {
        uint4 a0 = *(const uint4*)(A + arow + kt + shalf * 16);
        uint4 a1 = *(const uint4*)(A + arow + kt + shalf * 16 + 8);
        uint4 b0 = *(const uint4*)(Bt + brow + kt + shalf * 16);
        uint4 b1 = *(const uint4*)(Bt + brow + kt + shalf * 16 + 8);
        __syncthreads();
        *(uint4*)&As[srow * 40 + shalf * 16 + 0] = a0;
        *(uint4*)&As[srow * 40 + shalf * 16 + 8] = a1;
        *(uint4*)&Bs[srow * 40 + shalf * 16 + 0] = b0;
        *(uint4*)&Bs[srow * 40 + shalf * 16 + 8] = b1;
        __syncthreads();
        bf16x8 af[4], bf[4];
#pragma unroll
        for (int i = 0; i < 4; i++)
            af[i] = *(const bf16x8*)&As[(wm * 64 + i * 16 + cc) * 40 + quad * 8];
#pragma unroll
        for (int i = 0; i < 4; i++)
            bf[i] = *(const bf16x8*)&Bs[(wn * 64 + i * 16 + cc) * 40 + quad * 8];
#pragma unroll
        for (int i = 0; i < 4; i++)
#pragma unroll
            for (int j = 0; j < 4; j++)
                acc[i][j] = MFMA(af[i], bf[j], acc[i][j]);
    }

    if (EPI == 0) {
        const int e0 = n0 + wn * 64;          // 64-aligned -> single head per wave
        const int which = e0 >> 10;           // 0=q 1=k 2=v
        const int h = (e0 >> 6) & 15;
        if (which < 2) {
            unsigned short* dst = (which == 0) ? oq : ok;
#pragma unroll
            for (int mf = 0; mf < 4; mf++) {
#pragma unroll
                for (int r = 0; r < 4; r++) {
                    int mg = m0 + wm * 64 + mf * 16 + quad * 4 + r;
                    int nseq = mg & 2047, b = mg >> 11;
                    float vals[4];
#pragma unroll
                    for (int nf = 0; nf < 4; nf++) vals[nf] = acc[mf][nf][r];
                    size_t rowbase = ((size_t)(b * 16 + h) * 2048 + nseq) * 64;
#pragma unroll
                    for (int nf = 0; nf < 4; nf++) {
                        int d = nf * 16 + cc;
                        int f = d & 31;
                        float cs = cosT[nseq * 32 + f];
                        float sn = sinT[nseq * 32 + f];
                        float partner = vals[nf ^ 2];
                        float outv = vals[nf] * cs + ((nf < 2) ? -partner : partner) * sn;
                        dst[rowbase + d] = f2bf(outv);
                    }
                }
            }
        } else {
#pragma unroll
            for (int mf = 0; mf < 4; mf++) {
                int mg0 = m0 + wm * 64 + mf * 16 + quad * 4;
                int b = mg0 >> 11, nseq = mg0 & 2047;
#pragma unroll
                for (int nf = 0; nf < 4; nf++) {
                    int d = nf * 16 + cc;
                    ushort4 pk;
                    pk.x = f2bf(acc[mf][nf][0]);
                    pk.y = f2bf(acc[mf][nf][1]);
                    pk.z = f2bf(acc[mf][nf][2]);
                    pk.w = f2bf(acc[mf][nf][3]);
                    *(ushort4*)(ovt + ((size_t)(b * 16 + h) * 64 + d) * 2048 + nseq) = pk;
                }
            }
        }
    } else {
#pragma unroll
        for (int mf = 0; mf < 4; mf++)
#pragma unroll
            for (int nf = 0; nf < 4; nf++)
#pragma unroll
                for (int r = 0; r < 4; r++) {
                    int mg = m0 + wm * 64 + mf * 16 + quad * 4 + r;
                    of[(size_t)mg * Ncols + n0 + wn * 64 + nf * 16 + cc] = acc[mf][nf][r];
                }
    }
}

// ---------------- flash attention ----------------
// q,k: [B,H,N,D] bf16 ; vt: [B,H,D,N] bf16 ; o: [B,N,H*D] bf16
// block = 4 waves, Q-tile 128 rows (32/wave), Kt = 64

__global__ __launch_bounds__(256, 2) void attn(const unsigned short* __restrict__ q,
                                               const unsigned short* __restrict__ k,
                                               const unsigned short* __restrict__ vt,
                                               unsigned short* __restrict__ o) {
    __shared__ unsigned short qs[128 * 72];
    __shared__ unsigned short ks[64 * 72];
    __shared__ unsigned short vs[64 * 72];
    __shared__ unsigned short ps[128 * 72];
    const int tid = threadIdx.x;
    const int w = tid >> 6, lane = tid & 63, quad = lane >> 4, cc = lane & 15;
    const int bh = blockIdx.x >> 4, qt = blockIdx.x & 15;

    {   // stage Q tile: 2 threads per 64-elem row, 4 x uint4 each (FULL row!)
        const unsigned short* qg = q + ((size_t)bh * 2048 + qt * 128) * 64;
        int row = tid >> 1, hf = tid & 1;
#pragma unroll
        for (int j = 0; j < 4; j++)
            *(uint4*)&qs[row * 72 + hf * 32 + j * 8] =
                *(const uint4*)(qg + row * 64 + hf * 32 + j * 8);
    }

    f32x4 oacc[2][4] = {};
    float rm[2][4], rl[2][4];
#pragma unroll
    for (int mf = 0; mf < 2; mf++)
#pragma unroll
        for (int r = 0; r < 4; r++) { rm[mf][r] = -1e30f; rl[mf][r] = 0.0f; }

    const unsigned short* kg0 = k + (size_t)bh * 2048 * 64;
    const unsigned short* vg0 = vt + (size_t)bh * 64 * 2048;
    const int r4 = tid >> 2, ch = tid & 3;

    for (int kt = 0; kt < 32; kt++) {
        uint4 kv0 = *(const uint4*)(kg0 + (kt * 64 + r4) * 64 + ch * 16);
        uint4 kv1 = *(const uint4*)(kg0 + (kt * 64 + r4) * 64 + ch * 16 + 8);
        uint4 vv0 = *(const uint4*)(vg0 + r4 * 2048 + kt * 64 + ch * 16);
        uint4 vv1 = *(const uint4*)(vg0 + r4 * 2048 + kt * 64 + ch * 16 + 8);
        __syncthreads();   // previous iter's PV reads done
        *(uint4*)&ks[r4 * 72 + ch * 16 + 0] = kv0;
        *(uint4*)&ks[r4 * 72 + ch * 16 + 8] = kv1;
        *(uint4*)&vs[r4 * 72 + ch * 16 + 0] = vv0;
        *(uint4*)&vs[r4 * 72 + ch * 16 + 8] = vv1;
        __syncthreads();

        // S = Q K^T
        f32x4 s[2][4] = {};
#pragma unroll
        for (int kc = 0; kc < 2; kc++) {
            bf16x8 aq[2];
            aq[0] = *(const bf16x8*)&qs[(w * 32 + cc) * 72 + kc * 32 + quad * 8];
            aq[1] = *(const bf16x8*)&qs[(w * 32 + 16 + cc) * 72 + kc * 32 + quad * 8];
#pragma unroll
            for (int nf = 0; nf < 4; nf++) {
                bf16x8 bk = *(const bf16x8*)&ks[(nf * 16 + cc) * 72 + kc * 32 + quad * 8];
                s[0][nf] = MFMA(aq[0], bk, s[0][nf]);
                s[1][nf] = MFMA(aq[1], bk, s[1][nf]);
            }
        }

        // online softmax (rows quad*4+r live in the 16 lanes of a quad)
#pragma unroll
        for (int mf = 0; mf < 2; mf++) {
#pragma unroll
            for (int r = 0; r < 4; r++) {
                float v0 = s[mf][0][r] * 0.125f, v1 = s[mf][1][r] * 0.125f;
                float v2 = s[mf][2][r] * 0.125f, v3 = s[mf][3][r] * 0.125f;
                float mx = fmaxf(fmaxf(v0, v1), fmaxf(v2, v3));
#pragma unroll
                for (int off = 1; off < 16; off <<= 1)
                    mx = fmaxf(mx, __shfl_xor(mx, off, 64));
                float nm = fmaxf(rm[mf][r], mx);
                float alpha = __expf(rm[mf][r] - nm);
                rm[mf][r] = nm;
                float p0 = __expf(v0 - nm), p1 = __expf(v1 - nm);
                float p2 = __expf(v2 - nm), p3 = __expf(v3 - nm);
                float sum = p0 + p1 + p2 + p3;
#pragma unroll
                for (int off = 1; off < 16; off <<= 1)
                    sum += __shfl_xor(sum, off, 64);
                rl[mf][r] = rl[mf][r] * alpha + sum;
                s[mf][0][r] = p0; s[mf][1][r] = p1; s[mf][2][r] = p2; s[mf][3][r] = p3;
#pragma unroll
                for (int df = 0; df < 4; df++) oacc[mf][df][r] *= alpha;
            }
        }

        // P: C-layout -> LDS (row-major) ; each wave touches only its own 32 rows
#pragma unroll
        for (int mf = 0; mf < 2; mf++)
#pragma unroll
            for (int nf = 0; nf < 4; nf++)
#pragma unroll
                for (int r = 0; r < 4; r++)
                    ps[(w * 32 + mf * 16 + quad * 4 + r) * 72 + nf * 16 + cc] =
                        f2bf(s[mf][nf][r]);

        // O += P V
#pragma unroll
        for (int kc = 0; kc < 2; kc++) {
            bf16x8 ap[2];
            ap[0] = *(const bf16x8*)&ps[(w * 32 + cc) * 72 + kc * 32 + quad * 8];
            ap[1] = *(const bf16x8*)&ps[(w * 32 + 16 + cc) * 72 + kc * 32 + quad * 8];
#pragma unroll
            for (int df = 0; df < 4; df++) {
                bf16x8 bv = *(const bf16x8*)&vs[(df * 16 + cc) * 72 + kc * 32 + quad * 8];
                oacc[0][df] = MFMA(ap[0], bv, oacc[0][df]);
                oacc[1][df] = MFMA(ap[1], bv, oacc[1][df]);
            }
        }
    }

    __syncthreads();
#pragma unroll
    for (int mf = 0; mf < 2; mf++)
#pragma unroll
        for (int r = 0; r < 4; r++) {
            float inv = 1.0f / rl[mf][r];
#pragma unroll
            for (int df = 0; df < 4; df++)
                ps[(w * 32 + mf * 16 + quad * 4 + r) * 72 + df * 16 + cc] =
                    f2bf(oacc[mf][df][r] * inv);
        }
    __syncthreads();
    {
        const int b = bh >> 4, h = bh & 15;
        int row = tid >> 1, hf = tid & 1;
        unsigned short* og =
            o + ((size_t)(b * 2048 + qt * 128 + row)) * 1024 + h * 64 + hf * 32;
#pragma unroll
        for (int j = 0; j < 4; j++)
            *(uint4*)(og + j * 8) = *(const uint4*)&ps[row * 72 + hf * 32 + j * 8];
    }
}

// ---------------- launcher ----------------

extern "C" void kernel_launch(void* const* d_in, const int* in_sizes, int n_in,
                              void* d_out, int out_size, void* d_ws, size_t ws_size,
                              hipStream_t stream) {
    const float* x = (const float*)d_in[0];
    const float* w_qkv = (const float*)d_in[1];
    const float* w_out = (const float*)d_in[2];
    float* out = (float*)d_out;

    unsigned short* xb    = (unsigned short*)d_ws;        // 4096*1024
    unsigned short* wqkvT = xb + 4096 * 1024;             // 3072*1024
    unsigned short* woutT = wqkvT + 3072 * 1024;          // 1024*1024
    unsigned short* qb    = woutT + 1024 * 1024;          // 2*16*2048*64
    unsigned short* kb    = qb + 2 * 16 * 2048 * 64;
    unsigned short* vtb   = kb + 2 * 16 * 2048 * 64;
    unsigned short* ob    = vtb + 2 * 16 * 2048 * 64;     // 4096*1024
    float* cosT = (float*)(ob + 4096 * 1024);             // 2048*32 fp32
    float* sinT = cosT + 2048 * 32;

    rope_tab<<<256, 256, 0, stream>>>(cosT, sinT);
    cvt_bf16<<<4096, 256, 0, stream>>>(x, xb, 4096 * 1024);
    transpose_cvt<<<dim3(96, 32), 256, 0, stream>>>(w_qkv, wqkvT, 1024, 3072);
    transpose_cvt<<<dim3(32, 32), 256, 0, stream>>>(w_out, woutT, 1024, 1024);
    gemm_bt<0><<<dim3(24, 32), 256, 0, stream>>>(xb, wqkvT, 1024, 3072,
                                                 qb, kb, vtb, nullptr, cosT, sinT);
    attn<<<512, 256, 0, stream>>>(qb, kb, vtb, ob);
    gemm_bt<1><<<dim3(8, 32), 256, 0, stream>>>(ob, woutT, 1024, 1024,
                                                nullptr, nullptr, nullptr, out,
                                                nullptr, nullptr);
}